// Round 5
// baseline (180.645 us; speedup 1.0000x reference)
//
#include <hip/hip_runtime.h>
#include <math.h>

#define T_LEN    20000
#define NBC      1280      // 32*40
#define NTHREADS 256
#define CHUNK    80        // 250 active threads * 80 = 20000

// softplus-like immediate permeability
// p1 = log(exp(ln2*(PIMAX/PIREST)) - 1) = 34.657359027997266 (double)
// K  = p3/p1 = PIREST/ln2 = 0.017312340490667562
__device__ __forceinline__ float softplus_ppi(float x) {
    const float P1 = 34.657359027997266f;
    const float K  = 0.017312340490667562f;
    return K * log1pf(__expf(P1 * x));
}

__global__ __launch_bounds__(NTHREADS)
void na_scan_kernel(const float* __restrict__ ihcl, float* __restrict__ out) {
    const int bc  = blockIdx.x;
    const int tid = threadIdx.x;
    const long base = (long)bc * T_LEN;
    const int t0 = tid * CHUNK;

    // constants (reference: a_i = sper/VI = 0.1, a_l = sper/VL = 0.01)
    const float A_I = 0.1f;
    const float A_L = 0.01f;
    const float PLc = 0.06f;
    const float PGc = 0.03f;
    const float BE  = A_I * PLc;                  // 0.006
    const float GA  = A_L * PLc;                  // 0.0006
    const float DE  = 1.0f - A_L * (PLc + PGc);   // 0.9991
    const float CI0 = 4166.666666666667f;         // SPONT/PIREST
    const float CL0 = 5000.0f;                    // CI0*(PIREST+PL)/PL
    const float CG  = 6666.6669921875f;           // CL0*(1+PL/PG) - CI0*(PL/PG) in f32
    const float CLC = A_L * PGc * CG;             // constant term of CL row

    // ---------- Pass 1: compose affine map of this thread's chunk ----------
    // map: s_end = M * s_start + v
    float m00 = 1.f, m01 = 0.f, m10 = 0.f, m11 = 1.f, v0 = 0.f, v1 = 0.f;

    if (t0 < T_LEN) {
        const float4* src = reinterpret_cast<const float4*>(ihcl + base + t0);
        #pragma unroll 4
        for (int j = 0; j < CHUNK / 4; ++j) {
            float4 x4 = src[j];
            float xs[4] = {x4.x, x4.y, x4.z, x4.w};
            #pragma unroll
            for (int e = 0; e < 4; ++e) {
                if (t0 + j * 4 + e == 0) continue;   // t=0: identity (spont)
                float ppi = softplus_ppi(xs[e]);
                float al  = 1.0f - A_I * (ppi + PLc);
                // A = [[al, BE], [GA*al, GA*BE + DE]], b = (0, CLC)
                float nm00 = al * m00 + BE * m10;
                float nm01 = al * m01 + BE * m11;
                float nv0  = al * v0  + BE * v1;
                m10 = GA * nm00 + DE * m10;
                m11 = GA * nm01 + DE * m11;
                v1  = GA * nv0  + DE * v1 + CLC;
                m00 = nm00; m01 = nm01; v0 = nv0;
            }
        }
    }

    // ---------- Pass 2: inclusive Hillis-Steele scan of affine maps in LDS ----------
    __shared__ float s0[NTHREADS], s1[NTHREADS], s2[NTHREADS],
                     s3[NTHREADS], s4[NTHREADS], s5[NTHREADS];
    s0[tid] = m00; s1[tid] = m01; s2[tid] = m10; s3[tid] = m11;
    s4[tid] = v0;  s5[tid] = v1;
    __syncthreads();

    for (int d = 1; d < NTHREADS; d <<= 1) {
        float a00 = 0.f, a01 = 0.f, a10 = 0.f, a11 = 0.f, av0 = 0.f, av1 = 0.f;
        const bool act = (tid >= d);
        if (act) {
            a00 = s0[tid - d]; a01 = s1[tid - d];
            a10 = s2[tid - d]; a11 = s3[tid - d];
            av0 = s4[tid - d]; av1 = s5[tid - d];
        }
        __syncthreads();
        if (act) {
            // mine after left: M = M_mine*M_left ; v = M_mine*v_left + v_mine
            float r00 = m00 * a00 + m01 * a10;
            float r01 = m00 * a01 + m01 * a11;
            float r10 = m10 * a00 + m11 * a10;
            float r11 = m10 * a01 + m11 * a11;
            float rv0 = m00 * av0 + m01 * av1 + v0;
            float rv1 = m10 * av0 + m11 * av1 + v1;
            m00 = r00; m01 = r01; m10 = r10; m11 = r11; v0 = rv0; v1 = rv1;
            s0[tid] = m00; s1[tid] = m01; s2[tid] = m10; s3[tid] = m11;
            s4[tid] = v0;  s5[tid] = v1;
        }
        __syncthreads();
    }

    // exclusive prefix -> start state of this thread's chunk
    float CI = CI0, CL = CL0;
    if (tid > 0) {
        float e00 = s0[tid - 1], e01 = s1[tid - 1];
        float e10 = s2[tid - 1], e11 = s3[tid - 1];
        float ev0 = s4[tid - 1], ev1 = s5[tid - 1];
        CI = e00 * CI0 + e01 * CL0 + ev0;
        CL = e10 * CI0 + e11 * CL0 + ev1;
    }

    // ---------- Pass 3: replay chunk with exact reference update, write output ----------
    if (t0 < T_LEN) {
        const float4* src = reinterpret_cast<const float4*>(ihcl + base + t0);
        float* dst = out + base + t0;
        #pragma unroll 4
        for (int j = 0; j < CHUNK / 4; ++j) {
            float4 x4 = src[j];
            float xs[4] = {x4.x, x4.y, x4.z, x4.w};
            float os[4];
            #pragma unroll
            for (int e = 0; e < 4; ++e) {
                if (t0 + j * 4 + e == 0) { os[e] = 50.0f; continue; }
                float ppi = softplus_ppi(xs[e]);
                CI = CI + A_I * (-ppi * CI + PLc * (CL - CI));
                CL = CL + A_L * (-PLc * (CL - CI) + PGc * (CG - CL));
                os[e] = CI * ppi;
            }
            *reinterpret_cast<float4*>(dst + j * 4) =
                make_float4(os[0], os[1], os[2], os[3]);
        }
    }
}

extern "C" void kernel_launch(void* const* d_in, const int* in_sizes, int n_in,
                              void* d_out, int out_size, void* d_ws, size_t ws_size,
                              hipStream_t stream) {
    const float* ihcl = (const float*)d_in[0];
    float* out = (float*)d_out;
    na_scan_kernel<<<NBC, NTHREADS, 0, stream>>>(ihcl, out);
}

// Round 6
// 116.777 us; speedup vs baseline: 1.5469x; 1.5469x over previous
//
#include <hip/hip_runtime.h>
#include <math.h>

#define T_LEN    20000
#define NBC      1280      // 32*40
#define NTHREADS 256
#define CHUNK    80        // 250 active threads * 80 = 20000

// Immediate permeability:
//   ppi = (p3/p1) * log1p(exp(p1*x)),  p1 = ln2*(PIMAX/PIREST) = 50*ln2
// Base-2 identity (valid for ALL x, branch-free):
//   ppi = 0.012 * log2(1 + 2^(50x)) = 0.012 * (50x + log2(1 + 2^(-50x)))
// Compiles to: mul, v_exp_f32 (with free -src modifier), add, v_log_f32, add, mul.
__device__ __forceinline__ float softplus_ppi(float x) {
    float y = 50.0f * x;
    float t = __builtin_exp2f(-y);        // v_exp_f32
    float l = __builtin_log2f(1.0f + t);  // v_log_f32
    return 0.012f * (y + l);
}

__global__ __launch_bounds__(NTHREADS)
void na_scan_kernel(const float* __restrict__ ihcl, float* __restrict__ out) {
    const int bc  = blockIdx.x;
    const int tid = threadIdx.x;
    const long base = (long)bc * T_LEN;
    const int t0 = tid * CHUNK;

    // constants (reference: a_i = sper/VI = 0.1, a_l = sper/VL = 0.01)
    const float A_I = 0.1f;
    const float A_L = 0.01f;
    const float PLc = 0.06f;
    const float PGc = 0.03f;
    const float BE  = A_I * PLc;                  // 0.006
    const float GA  = A_L * PLc;                  // 0.0006
    const float DE  = 1.0f - A_L * (PLc + PGc);   // 0.9991
    const float CI0 = 4166.666666666667f;         // SPONT/PIREST
    const float CL0 = 5000.0f;                    // CI0*(PIREST+PL)/PL
    const float CG  = 6666.6669921875f;           // CL0*(1+PL/PG) - CI0*(PL/PG) in f32
    const float CLC = A_L * PGc * CG;             // constant term of CL row

    // ---------- Pass 1: compose affine map of this thread's chunk ----------
    // map: s_end = M * s_start + v
    float m00 = 1.f, m01 = 0.f, m10 = 0.f, m11 = 1.f, v0 = 0.f, v1 = 0.f;

    if (t0 < T_LEN) {
        const float4* src = reinterpret_cast<const float4*>(ihcl + base + t0);
        #pragma unroll 4
        for (int j = 0; j < CHUNK / 4; ++j) {
            float4 x4 = src[j];
            float xs[4] = {x4.x, x4.y, x4.z, x4.w};
            #pragma unroll
            for (int e = 0; e < 4; ++e) {
                if (t0 + j * 4 + e == 0) continue;   // t=0: identity (spont)
                float ppi = softplus_ppi(xs[e]);
                float al  = 1.0f - A_I * (ppi + PLc);
                // A = [[al, BE], [GA*al, GA*BE + DE]], b = (0, CLC)
                float nm00 = al * m00 + BE * m10;
                float nm01 = al * m01 + BE * m11;
                float nv0  = al * v0  + BE * v1;
                m10 = GA * nm00 + DE * m10;
                m11 = GA * nm01 + DE * m11;
                v1  = GA * nv0  + DE * v1 + CLC;
                m00 = nm00; m01 = nm01; v0 = nv0;
            }
        }
    }

    // ---------- Pass 2: inclusive Hillis-Steele scan of affine maps in LDS ----------
    __shared__ float s0[NTHREADS], s1[NTHREADS], s2[NTHREADS],
                     s3[NTHREADS], s4[NTHREADS], s5[NTHREADS];
    s0[tid] = m00; s1[tid] = m01; s2[tid] = m10; s3[tid] = m11;
    s4[tid] = v0;  s5[tid] = v1;
    __syncthreads();

    for (int d = 1; d < NTHREADS; d <<= 1) {
        float a00 = 0.f, a01 = 0.f, a10 = 0.f, a11 = 0.f, av0 = 0.f, av1 = 0.f;
        const bool act = (tid >= d);
        if (act) {
            a00 = s0[tid - d]; a01 = s1[tid - d];
            a10 = s2[tid - d]; a11 = s3[tid - d];
            av0 = s4[tid - d]; av1 = s5[tid - d];
        }
        __syncthreads();
        if (act) {
            // mine after left: M = M_mine*M_left ; v = M_mine*v_left + v_mine
            float r00 = m00 * a00 + m01 * a10;
            float r01 = m00 * a01 + m01 * a11;
            float r10 = m10 * a00 + m11 * a10;
            float r11 = m10 * a01 + m11 * a11;
            float rv0 = m00 * av0 + m01 * av1 + v0;
            float rv1 = m10 * av0 + m11 * av1 + v1;
            m00 = r00; m01 = r01; m10 = r10; m11 = r11; v0 = rv0; v1 = rv1;
            s0[tid] = m00; s1[tid] = m01; s2[tid] = m10; s3[tid] = m11;
            s4[tid] = v0;  s5[tid] = v1;
        }
        __syncthreads();
    }

    // exclusive prefix -> start state of this thread's chunk
    float CI = CI0, CL = CL0;
    if (tid > 0) {
        float e00 = s0[tid - 1], e01 = s1[tid - 1];
        float e10 = s2[tid - 1], e11 = s3[tid - 1];
        float ev0 = s4[tid - 1], ev1 = s5[tid - 1];
        CI = e00 * CI0 + e01 * CL0 + ev0;
        CL = e10 * CI0 + e11 * CL0 + ev1;
    }

    // ---------- Pass 3: replay chunk with exact reference update, write output ----------
    if (t0 < T_LEN) {
        const float4* src = reinterpret_cast<const float4*>(ihcl + base + t0);
        float* dst = out + base + t0;
        #pragma unroll 4
        for (int j = 0; j < CHUNK / 4; ++j) {
            float4 x4 = src[j];
            float xs[4] = {x4.x, x4.y, x4.z, x4.w};
            float os[4];
            #pragma unroll
            for (int e = 0; e < 4; ++e) {
                if (t0 + j * 4 + e == 0) { os[e] = 50.0f; continue; }
                float ppi = softplus_ppi(xs[e]);
                CI = CI + A_I * (-ppi * CI + PLc * (CL - CI));
                CL = CL + A_L * (-PLc * (CL - CI) + PGc * (CG - CL));
                os[e] = CI * ppi;
            }
            *reinterpret_cast<float4*>(dst + j * 4) =
                make_float4(os[0], os[1], os[2], os[3]);
        }
    }
}

extern "C" void kernel_launch(void* const* d_in, const int* in_sizes, int n_in,
                              void* d_out, int out_size, void* d_ws, size_t ws_size,
                              hipStream_t stream) {
    const float* ihcl = (const float*)d_in[0];
    float* out = (float*)d_out;
    na_scan_kernel<<<NBC, NTHREADS, 0, stream>>>(ihcl, out);
}